// Round 2
// baseline (305.486 us; speedup 1.0000x reference)
//
#include <hip/hip_runtime.h>
#include <hip/hip_bf16.h>

typedef __attribute__((ext_vector_type(8))) short short8;
typedef __attribute__((ext_vector_type(4))) float floatx4;

#define BDIM 128
#define RDIM 1024
#define NB   4096
#define NG   16

__device__ __forceinline__ float mishf(float x) {
    // mish(x) = x * tanh(softplus(x)) = x * t/(t+2), t = e*(e+2), e = exp(x)
    float e = __expf(x);
    float t = e * (e + 2.0f);
    float r = x * (t / (t + 2.0f));
    return x > 20.0f ? x : r;   // avoid inf/inf NaN for large x
}

// load 8 consecutive fp32, convert RNE to 8 bf16 packed in short8 (MFMA A/B frag)
__device__ __forceinline__ short8 cvt8(const float* __restrict__ p) {
    const float4* q = (const float4*)p;
    float4 f0 = q[0];
    float4 f1 = q[1];
    union { __hip_bfloat162 h; unsigned u; } c0, c1, c2, c3;
    c0.h = __float22bfloat162_rn(make_float2(f0.x, f0.y));
    c1.h = __float22bfloat162_rn(make_float2(f0.z, f0.w));
    c2.h = __float22bfloat162_rn(make_float2(f1.x, f1.y));
    c3.h = __float22bfloat162_rn(make_float2(f1.z, f1.w));
    union { short8 s; unsigned u[4]; } r;
    r.u[0] = c0.u; r.u[1] = c1.u; r.u[2] = c2.u; r.u[3] = c3.u;
    return r.s;
}

// ---------------- BB mean over G (=16) -> ws fp32 ----------------
__global__ void __launch_bounds__(256) k_mean(const float* __restrict__ bb,
                                              float* __restrict__ mean) {
    int tid = blockIdx.x * blockDim.x + threadIdx.x;   // 131072 threads
    int b = tid >> 5;
    int d = (tid & 31) * 4;
    const float4* p = (const float4*)(bb + (size_t)b * (NG * BDIM) + d);
    float4 s = {0.f, 0.f, 0.f, 0.f};
    #pragma unroll
    for (int g = 0; g < NG; ++g) {
        float4 v = p[g * (BDIM / 4)];
        s.x += v.x; s.y += v.y; s.z += v.z; s.w += v.w;
    }
    s.x *= 0.0625f; s.y *= 0.0625f; s.z *= 0.0625f; s.w *= 0.0625f;
    *(float4*)(mean + (size_t)b * BDIM + d) = s;
}

// ---------------- RF_to_BB = mish(RF @ W_rfbb^T + b) -> ws fp32 ----------------
__global__ void __launch_bounds__(256) k_rf2bb(
    const float* __restrict__ rf,    // [4096,1024]
    const float* __restrict__ W,     // [128,1024]
    const float* __restrict__ bias,  // [128]
    float* __restrict__ outw)        // [4096,128]
{
    int wave = (blockIdx.x << 2) + (threadIdx.x >> 6);  // 2048 waves
    int lane = threadIdx.x & 63;
    int r = lane & 15, quad = lane >> 4, koff = quad * 8;
    int mt = wave >> 3, nt = wave & 7;
    int m0 = mt * 16, n0 = nt * 16;
    floatx4 acc = {0.f, 0.f, 0.f, 0.f};
    const float* ap = rf + (size_t)(m0 + r) * RDIM + koff;
    const float* bp = W  + (size_t)(n0 + r) * RDIM + koff;
    for (int k = 0; k < RDIM; k += 32) {
        acc = __builtin_amdgcn_mfma_f32_16x16x32_bf16(cvt8(ap + k), cvt8(bp + k), acc, 0, 0, 0);
    }
    int col = n0 + r;
    float bs = bias[col];
    #pragma unroll
    for (int g = 0; g < 4; ++g) {
        int row = m0 + quad * 4 + g;   // D: row = quad*4+reg, col = lane&15
        outw[(size_t)row * BDIM + col] = mishf(acc[g] + bs);
    }
}

// ---------------- new_RF = mish(RF@W_rfrf^T+b1) + mish(mean@W_bbrf^T+b2) ----------------
__global__ void __launch_bounds__(256) k_newrf(
    const float* __restrict__ rf,     // [4096,1024]
    const float* __restrict__ mean,   // [4096,128]  (ws, fp32)
    const float* __restrict__ Wrfrf,  // [1024,1024]
    const float* __restrict__ brfrf,  // [1024]
    const float* __restrict__ Wbbrf,  // [1024,128]
    const float* __restrict__ bbbrf,  // [1024]
    float* __restrict__ out)          // [4096,1024]
{
    int wave = (blockIdx.x << 2) + (threadIdx.x >> 6);  // 4096 waves
    int lane = threadIdx.x & 63;
    int r = lane & 15, quad = lane >> 4, koff = quad * 8;
    int mt = wave >> 5, nt = wave & 31;
    int m0 = mt * 32, n0 = nt * 32;

    floatx4 a00 = {0.f,0.f,0.f,0.f}, a01 = a00, a10 = a00, a11 = a00;
    {
        const float* a0p = rf + (size_t)(m0 + r) * RDIM + koff;
        const float* a1p = a0p + 16 * RDIM;
        const float* b0p = Wrfrf + (size_t)(n0 + r) * RDIM + koff;
        const float* b1p = b0p + 16 * RDIM;
        for (int k = 0; k < RDIM; k += 32) {
            short8 a0 = cvt8(a0p + k), a1 = cvt8(a1p + k);
            short8 b0 = cvt8(b0p + k), b1 = cvt8(b1p + k);
            a00 = __builtin_amdgcn_mfma_f32_16x16x32_bf16(a0, b0, a00, 0, 0, 0);
            a01 = __builtin_amdgcn_mfma_f32_16x16x32_bf16(a0, b1, a01, 0, 0, 0);
            a10 = __builtin_amdgcn_mfma_f32_16x16x32_bf16(a1, b0, a10, 0, 0, 0);
            a11 = __builtin_amdgcn_mfma_f32_16x16x32_bf16(a1, b1, a11, 0, 0, 0);
        }
    }
    floatx4 c00 = {0.f,0.f,0.f,0.f}, c01 = c00, c10 = c00, c11 = c00;
    {
        const float* a0p = mean + (size_t)(m0 + r) * BDIM + koff;
        const float* a1p = a0p + 16 * BDIM;
        const float* b0p = Wbbrf + (size_t)(n0 + r) * BDIM + koff;
        const float* b1p = b0p + 16 * BDIM;
        #pragma unroll
        for (int k = 0; k < BDIM; k += 32) {
            short8 a0 = cvt8(a0p + k), a1 = cvt8(a1p + k);
            short8 b0 = cvt8(b0p + k), b1 = cvt8(b1p + k);
            c00 = __builtin_amdgcn_mfma_f32_16x16x32_bf16(a0, b0, c00, 0, 0, 0);
            c01 = __builtin_amdgcn_mfma_f32_16x16x32_bf16(a0, b1, c01, 0, 0, 0);
            c10 = __builtin_amdgcn_mfma_f32_16x16x32_bf16(a1, b0, c10, 0, 0, 0);
            c11 = __builtin_amdgcn_mfma_f32_16x16x32_bf16(a1, b1, c11, 0, 0, 0);
        }
    }
    floatx4 g1[2][2] = {{a00, a01}, {a10, a11}};
    floatx4 g2[2][2] = {{c00, c01}, {c10, c11}};
    #pragma unroll
    for (int i = 0; i < 2; ++i) {
        #pragma unroll
        for (int j = 0; j < 2; ++j) {
            int col = n0 + j * 16 + r;
            float b1 = brfrf[col];
            float b2 = bbbrf[col];
            #pragma unroll
            for (int g = 0; g < 4; ++g) {
                int row = m0 + i * 16 + quad * 4 + g;
                float v = mishf(g1[i][j][g] + b1) + mishf(g2[i][j][g] + b2);
                out[(size_t)row * RDIM + col] = v;
            }
        }
    }
}

// ---------------- new_BB = mish(BB @ W_bbbb^T + b) + RF_to_BB[b] ----------------
__global__ void __launch_bounds__(256) k_newbb(
    const float* __restrict__ bb,    // [65536,128]
    const float* __restrict__ W,     // [128,128]
    const float* __restrict__ bias,  // [128]
    const float* __restrict__ rf2bb, // [4096,128] (ws, fp32)
    float* __restrict__ out)         // [65536,128]
{
    int wave = (blockIdx.x << 2) + (threadIdx.x >> 6);  // 4096 waves
    int lane = threadIdx.x & 63;
    int r = lane & 15, quad = lane >> 4, koff = quad * 8;
    int m0 = wave * 16;
    floatx4 acc[8];
    #pragma unroll
    for (int j = 0; j < 8; ++j) acc[j] = floatx4{0.f, 0.f, 0.f, 0.f};
    const float* ap = bb + (size_t)(m0 + r) * BDIM + koff;
    #pragma unroll
    for (int k = 0; k < BDIM; k += 32) {
        short8 a = cvt8(ap + k);
        #pragma unroll
        for (int j = 0; j < 8; ++j) {
            short8 b = cvt8(W + (size_t)(j * 16 + r) * BDIM + k + koff);
            acc[j] = __builtin_amdgcn_mfma_f32_16x16x32_bf16(a, b, acc[j], 0, 0, 0);
        }
    }
    #pragma unroll
    for (int j = 0; j < 8; ++j) {
        int col = j * 16 + r;
        float bs = bias[col];
        #pragma unroll
        for (int g = 0; g < 4; ++g) {
            int row = m0 + quad * 4 + g;
            float v = mishf(acc[j][g] + bs) + rf2bb[(size_t)(row >> 4) * BDIM + col];
            out[(size_t)row * BDIM + col] = v;
        }
    }
}

extern "C" void kernel_launch(void* const* d_in, const int* in_sizes, int n_in,
                              void* d_out, int out_size, void* d_ws, size_t ws_size,
                              hipStream_t stream) {
    const float* BB    = (const float*)d_in[0];  // [4096,16,128]
    const float* RF    = (const float*)d_in[1];  // [4096,1024]
    const float* Wrfbb = (const float*)d_in[2];  // [128,1024]
    const float* brfbb = (const float*)d_in[3];  // [128]
    const float* Wrfrf = (const float*)d_in[4];  // [1024,1024]
    const float* brfrf = (const float*)d_in[5];  // [1024]
    const float* Wbbrf = (const float*)d_in[6];  // [1024,128]
    const float* bbbrf = (const float*)d_in[7];  // [1024]
    const float* Wbbbb = (const float*)d_in[8];  // [128,128]
    const float* bbbbb = (const float*)d_in[9];  // [128]

    float* outBB = (float*)d_out;                     // 4096*16*128
    float* outRF = outBB + (size_t)NB * NG * BDIM;    // 4096*1024

    float* mean  = (float*)d_ws;                                  // 2 MB
    float* rf2bb = (float*)((char*)d_ws + (size_t)NB * BDIM * 4); // 2 MB

    k_mean <<<512,  256, 0, stream>>>(BB, mean);
    k_rf2bb<<<512,  256, 0, stream>>>(RF, Wrfbb, brfbb, rf2bb);
    k_newrf<<<1024, 256, 0, stream>>>(RF, mean, Wrfrf, brfrf, Wbbrf, bbbrf, outRF);
    k_newbb<<<1024, 256, 0, stream>>>(BB, Wbbbb, bbbbb, rf2bb, outBB);
}

// Round 3
// 187.787 us; speedup vs baseline: 1.6268x; 1.6268x over previous
//
#include <hip/hip_runtime.h>
#include <hip/hip_bf16.h>

typedef __attribute__((ext_vector_type(8))) short short8;
typedef __attribute__((ext_vector_type(4))) float floatx4;

#define BDIM 128
#define RDIM 1024
#define NB   4096
#define NG   16
#define LDP  40   // padded LDS row stride (bf16 elems): 80 B -> 2-way bank alias (free)

__device__ __forceinline__ float mishf(float x) {
    float e = __expf(x);
    float t = e * (e + 2.0f);
    float r = x * (t / (t + 2.0f));
    return x > 20.0f ? x : r;
}

__device__ __forceinline__ short8 cvt8v(float4 f0, float4 f1) {
    union { __hip_bfloat162 h; unsigned u; } c0, c1, c2, c3;
    c0.h = __float22bfloat162_rn(make_float2(f0.x, f0.y));
    c1.h = __float22bfloat162_rn(make_float2(f0.z, f0.w));
    c2.h = __float22bfloat162_rn(make_float2(f1.x, f1.y));
    c3.h = __float22bfloat162_rn(make_float2(f1.z, f1.w));
    union { short8 s; unsigned u[4]; } r;
    r.u[0] = c0.u; r.u[1] = c1.u; r.u[2] = c2.u; r.u[3] = c3.u;
    return r.s;
}

#define MFMA(a, b, c) __builtin_amdgcn_mfma_f32_16x16x32_bf16(a, b, c, 0, 0, 0)

// ---------------- BB mean over G (=16) -> ws fp32 ----------------
__global__ void __launch_bounds__(256) k_mean(const float* __restrict__ bb,
                                              float* __restrict__ mean) {
    int tid = blockIdx.x * blockDim.x + threadIdx.x;   // 131072 threads
    int b = tid >> 5;
    int d = (tid & 31) * 4;
    const float4* p = (const float4*)(bb + (size_t)b * (NG * BDIM) + d);
    float4 s = {0.f, 0.f, 0.f, 0.f};
    #pragma unroll
    for (int g = 0; g < NG; ++g) {
        float4 v = p[g * (BDIM / 4)];
        s.x += v.x; s.y += v.y; s.z += v.z; s.w += v.w;
    }
    s.x *= 0.0625f; s.y *= 0.0625f; s.z *= 0.0625f; s.w *= 0.0625f;
    *(float4*)(mean + (size_t)b * BDIM + d) = s;
}

// ---------------- RF_to_BB = mish(RF @ W_rfbb^T + b) -> ws fp32 ----------------
// 256 blocks x 256 thr; block: 16 rows x 128 cols, K=1024 in 32-chunks.
__global__ void __launch_bounds__(256) k_rf2bb(
    const float* __restrict__ rf,    // [4096,1024]
    const float* __restrict__ W,     // [128,1024]
    const float* __restrict__ bias,  // [128]
    float* __restrict__ outw)        // [4096,128]
{
    __shared__ short As[16 * LDP];
    __shared__ short Bs[128 * LDP];
    int tid = threadIdx.x;
    int wave = tid >> 6, lane = tid & 63;
    int r = lane & 15, quad = lane >> 4;
    int m0 = blockIdx.x * 16;
    int srow = tid >> 2, sks = tid & 3;

    const float* aG  = rf + (size_t)(m0 + srow) * RDIM + sks * 8;      // tid<64 only
    const float* bG0 = W  + (size_t)srow * RDIM + sks * 8;             // rows 0..63
    const float* bG1 = W  + (size_t)(64 + srow) * RDIM + sks * 8;      // rows 64..127

    float4 qa0, qa1, qb00, qb01, qb10, qb11;
    if (tid < 64) { qa0 = *(const float4*)aG; qa1 = *(const float4*)(aG + 4); }
    qb00 = *(const float4*)bG0; qb01 = *(const float4*)(bG0 + 4);
    qb10 = *(const float4*)bG1; qb11 = *(const float4*)(bG1 + 4);

    floatx4 acc[2];
    acc[0] = floatx4{0.f,0.f,0.f,0.f}; acc[1] = acc[0];

    for (int it = 0; it < 32; ++it) {
        __syncthreads();
        if (tid < 64) *(short8*)&As[srow * LDP + sks * 8] = cvt8v(qa0, qa1);
        *(short8*)&Bs[srow * LDP + sks * 8]        = cvt8v(qb00, qb01);
        *(short8*)&Bs[(64 + srow) * LDP + sks * 8] = cvt8v(qb10, qb11);
        __syncthreads();
        if (it < 31) {
            int k = (it + 1) * 32;
            if (tid < 64) { qa0 = *(const float4*)(aG + k); qa1 = *(const float4*)(aG + k + 4); }
            qb00 = *(const float4*)(bG0 + k); qb01 = *(const float4*)(bG0 + k + 4);
            qb10 = *(const float4*)(bG1 + k); qb11 = *(const float4*)(bG1 + k + 4);
        }
        short8 a = *(short8*)&As[r * LDP + quad * 8];
        #pragma unroll
        for (int nj = 0; nj < 2; ++nj) {
            short8 b = *(short8*)&Bs[(wave * 32 + nj * 16 + r) * LDP + quad * 8];
            acc[nj] = MFMA(a, b, acc[nj]);
        }
    }
    #pragma unroll
    for (int nj = 0; nj < 2; ++nj) {
        int col = wave * 32 + nj * 16 + r;
        float bs = bias[col];
        #pragma unroll
        for (int g = 0; g < 4; ++g) {
            int row = m0 + quad * 4 + g;
            outw[(size_t)row * BDIM + col] = mishf(acc[nj][g] + bs);
        }
    }
}

// ---------------- new_RF = mish(RF@W_rfrf^T+b1) + mish(mean@W_bbrf^T+b2) ----------------
// 256 blocks x 512 thr; block tile 128x128; wave tile 32x64.
__global__ void __launch_bounds__(512) k_newrf(
    const float* __restrict__ rf,     // [4096,1024]
    const float* __restrict__ meanp,  // [4096,128]
    const float* __restrict__ Wrfrf,  // [1024,1024]
    const float* __restrict__ brfrf,  // [1024]
    const float* __restrict__ Wbbrf,  // [1024,128]
    const float* __restrict__ bbbrf,  // [1024]
    float* __restrict__ out)          // [4096,1024]
{
    __shared__ short As[128 * LDP];
    __shared__ short Bs[128 * LDP];
    int tid = threadIdx.x;
    int wave = tid >> 6, lane = tid & 63;
    int r = lane & 15, quad = lane >> 4;
    int w_m = (wave & 3) * 32, w_n = (wave >> 2) * 64;
    int mt = blockIdx.x >> 3, nt = blockIdx.x & 7;
    int m0 = mt * 128, n0 = nt * 128;
    int srow = tid >> 2, sks = tid & 3;
    int sidx = srow * LDP + sks * 8;

    // ---- GEMM1: RF @ Wrfrf^T, K=1024 ----
    const float* aG = rf    + (size_t)(m0 + srow) * RDIM + sks * 8;
    const float* bG = Wrfrf + (size_t)(n0 + srow) * RDIM + sks * 8;
    float4 pa0 = *(const float4*)aG, pa1 = *(const float4*)(aG + 4);
    float4 pb0 = *(const float4*)bG, pb1 = *(const float4*)(bG + 4);

    floatx4 acc1[2][4], acc2[2][4];
    #pragma unroll
    for (int i = 0; i < 2; ++i)
        #pragma unroll
        for (int j = 0; j < 4; ++j) { acc1[i][j] = floatx4{0.f,0.f,0.f,0.f}; acc2[i][j] = acc1[i][j]; }

    for (int it = 0; it < 32; ++it) {
        __syncthreads();
        *(short8*)&As[sidx] = cvt8v(pa0, pa1);
        *(short8*)&Bs[sidx] = cvt8v(pb0, pb1);
        __syncthreads();
        if (it < 31) {
            int k = (it + 1) * 32;
            pa0 = *(const float4*)(aG + k); pa1 = *(const float4*)(aG + k + 4);
            pb0 = *(const float4*)(bG + k); pb1 = *(const float4*)(bG + k + 4);
        }
        short8 a0 = *(short8*)&As[(w_m + r) * LDP + quad * 8];
        short8 a1 = *(short8*)&As[(w_m + 16 + r) * LDP + quad * 8];
        #pragma unroll
        for (int nj = 0; nj < 4; ++nj) {
            short8 b = *(short8*)&Bs[(w_n + nj * 16 + r) * LDP + quad * 8];
            acc1[0][nj] = MFMA(a0, b, acc1[0][nj]);
            acc1[1][nj] = MFMA(a1, b, acc1[1][nj]);
        }
    }

    // ---- GEMM2: mean @ Wbbrf^T, K=128 ----
    const float* a2G = meanp + (size_t)(m0 + srow) * BDIM + sks * 8;
    const float* b2G = Wbbrf + (size_t)(n0 + srow) * BDIM + sks * 8;
    pa0 = *(const float4*)a2G; pa1 = *(const float4*)(a2G + 4);
    pb0 = *(const float4*)b2G; pb1 = *(const float4*)(b2G + 4);
    for (int it = 0; it < 4; ++it) {
        __syncthreads();
        *(short8*)&As[sidx] = cvt8v(pa0, pa1);
        *(short8*)&Bs[sidx] = cvt8v(pb0, pb1);
        __syncthreads();
        if (it < 3) {
            int k = (it + 1) * 32;
            pa0 = *(const float4*)(a2G + k); pa1 = *(const float4*)(a2G + k + 4);
            pb0 = *(const float4*)(b2G + k); pb1 = *(const float4*)(b2G + k + 4);
        }
        short8 a0 = *(short8*)&As[(w_m + r) * LDP + quad * 8];
        short8 a1 = *(short8*)&As[(w_m + 16 + r) * LDP + quad * 8];
        #pragma unroll
        for (int nj = 0; nj < 4; ++nj) {
            short8 b = *(short8*)&Bs[(w_n + nj * 16 + r) * LDP + quad * 8];
            acc2[0][nj] = MFMA(a0, b, acc2[0][nj]);
            acc2[1][nj] = MFMA(a1, b, acc2[1][nj]);
        }
    }

    #pragma unroll
    for (int mi = 0; mi < 2; ++mi) {
        #pragma unroll
        for (int nj = 0; nj < 4; ++nj) {
            int col = n0 + w_n + nj * 16 + r;
            float b1 = brfrf[col];
            float b2 = bbbrf[col];
            #pragma unroll
            for (int g = 0; g < 4; ++g) {
                int row = m0 + w_m + mi * 16 + quad * 4 + g;
                out[(size_t)row * RDIM + col] = mishf(acc1[mi][nj][g] + b1) + mishf(acc2[mi][nj][g] + b2);
            }
        }
    }
}

// ---------------- new_BB = mish(BB @ W_bbbb^T + b) + RF_to_BB[b] ----------------
// 512 blocks x 256 thr; block tile 128(M)x128(N), K=128 in 32-chunks; wave tile 32x128.
__global__ void __launch_bounds__(256) k_newbb(
    const float* __restrict__ bb,    // [65536,128]
    const float* __restrict__ W,     // [128,128]
    const float* __restrict__ bias,  // [128]
    const float* __restrict__ rf2bb, // [4096,128]
    float* __restrict__ out)         // [65536,128]
{
    __shared__ short As[128 * LDP];
    __shared__ short Ws[128 * LDP];
    int tid = threadIdx.x;
    int wave = tid >> 6, lane = tid & 63;
    int r = lane & 15, quad = lane >> 4;
    size_t m0 = (size_t)blockIdx.x * 128;
    int srow = tid >> 2, sks = tid & 3;

    const float* aG0 = bb + (m0 + srow) * BDIM + sks * 8;
    const float* aG1 = bb + (m0 + 64 + srow) * BDIM + sks * 8;
    const float* wG0 = W + (size_t)srow * BDIM + sks * 8;
    const float* wG1 = W + (size_t)(64 + srow) * BDIM + sks * 8;

    float4 qa00 = *(const float4*)aG0, qa01 = *(const float4*)(aG0 + 4);
    float4 qa10 = *(const float4*)aG1, qa11 = *(const float4*)(aG1 + 4);
    float4 qw00 = *(const float4*)wG0, qw01 = *(const float4*)(wG0 + 4);
    float4 qw10 = *(const float4*)wG1, qw11 = *(const float4*)(wG1 + 4);

    floatx4 acc[2][8];
    #pragma unroll
    for (int i = 0; i < 2; ++i)
        #pragma unroll
        for (int j = 0; j < 8; ++j) acc[i][j] = floatx4{0.f,0.f,0.f,0.f};

    for (int kc = 0; kc < 4; ++kc) {
        __syncthreads();
        *(short8*)&As[srow * LDP + sks * 8]        = cvt8v(qa00, qa01);
        *(short8*)&As[(64 + srow) * LDP + sks * 8] = cvt8v(qa10, qa11);
        *(short8*)&Ws[srow * LDP + sks * 8]        = cvt8v(qw00, qw01);
        *(short8*)&Ws[(64 + srow) * LDP + sks * 8] = cvt8v(qw10, qw11);
        __syncthreads();
        if (kc < 3) {
            int k = (kc + 1) * 32;
            qa00 = *(const float4*)(aG0 + k); qa01 = *(const float4*)(aG0 + k + 4);
            qa10 = *(const float4*)(aG1 + k); qa11 = *(const float4*)(aG1 + k + 4);
            qw00 = *(const float4*)(wG0 + k); qw01 = *(const float4*)(wG0 + k + 4);
            qw10 = *(const float4*)(wG1 + k); qw11 = *(const float4*)(wG1 + k + 4);
        }
        short8 a0 = *(short8*)&As[(wave * 32 + r) * LDP + quad * 8];
        short8 a1 = *(short8*)&As[(wave * 32 + 16 + r) * LDP + quad * 8];
        #pragma unroll
        for (int nj = 0; nj < 8; ++nj) {
            short8 b = *(short8*)&Ws[(nj * 16 + r) * LDP + quad * 8];
            acc[0][nj] = MFMA(a0, b, acc[0][nj]);
            acc[1][nj] = MFMA(a1, b, acc[1][nj]);
        }
    }

    #pragma unroll
    for (int mi = 0; mi < 2; ++mi) {
        #pragma unroll
        for (int nj = 0; nj < 8; ++nj) {
            int col = nj * 16 + r;
            float bs = bias[col];
            #pragma unroll
            for (int g = 0; g < 4; ++g) {
                size_t row = m0 + wave * 32 + mi * 16 + quad * 4 + g;
                out[row * BDIM + col] = mishf(acc[mi][nj][g] + bs) + rf2bb[(row >> 4) * BDIM + col];
            }
        }
    }
}

extern "C" void kernel_launch(void* const* d_in, const int* in_sizes, int n_in,
                              void* d_out, int out_size, void* d_ws, size_t ws_size,
                              hipStream_t stream) {
    const float* BB    = (const float*)d_in[0];
    const float* RF    = (const float*)d_in[1];
    const float* Wrfbb = (const float*)d_in[2];
    const float* brfbb = (const float*)d_in[3];
    const float* Wrfrf = (const float*)d_in[4];
    const float* brfrf = (const float*)d_in[5];
    const float* Wbbrf = (const float*)d_in[6];
    const float* bbbrf = (const float*)d_in[7];
    const float* Wbbbb = (const float*)d_in[8];
    const float* bbbbb = (const float*)d_in[9];

    float* outBB = (float*)d_out;
    float* outRF = outBB + (size_t)NB * NG * BDIM;

    float* mean  = (float*)d_ws;
    float* rf2bb = (float*)((char*)d_ws + (size_t)NB * BDIM * 4);

    k_mean <<<512, 256, 0, stream>>>(BB, mean);
    k_rf2bb<<<256, 256, 0, stream>>>(RF, Wrfbb, brfbb, rf2bb);
    k_newrf<<<256, 512, 0, stream>>>(RF, mean, Wrfrf, brfrf, Wbbrf, bbbrf, outRF);
    k_newbb<<<512, 256, 0, stream>>>(BB, Wbbbb, bbbbb, rf2bb, outBB);
}

// Round 4
// 162.618 us; speedup vs baseline: 1.8786x; 1.1548x over previous
//
#include <hip/hip_runtime.h>
#include <hip/hip_bf16.h>

typedef __attribute__((ext_vector_type(8))) short short8;
typedef __attribute__((ext_vector_type(4))) float floatx4;

#define BDIM 128
#define RDIM 1024
#define NB   4096
#define NG   16
#define LDP  40    // LDS row stride in shorts (80 B): 2-way bank alias = free
#define WSTR 136   // W-tile stride in k_newbb (272 B)

__device__ __forceinline__ float mishf(float x) {
    float e = __expf(x);
    float t = e * (e + 2.0f);
    float r = x * (t / (t + 2.0f));
    return x > 20.0f ? x : r;
}

__device__ __forceinline__ short8 cvt8v(float4 f0, float4 f1) {
    union { __hip_bfloat162 h; unsigned u; } c0, c1, c2, c3;
    c0.h = __float22bfloat162_rn(make_float2(f0.x, f0.y));
    c1.h = __float22bfloat162_rn(make_float2(f0.z, f0.w));
    c2.h = __float22bfloat162_rn(make_float2(f1.x, f1.y));
    c3.h = __float22bfloat162_rn(make_float2(f1.z, f1.w));
    union { short8 s; unsigned u[4]; } r;
    r.u[0] = c0.u; r.u[1] = c1.u; r.u[2] = c2.u; r.u[3] = c3.u;
    return r.s;
}

#define MFMA(a, b, c) __builtin_amdgcn_mfma_f32_16x16x32_bf16(a, b, c, 0, 0, 0)

// ---------------- BB mean over G (=16) -> ws fp32 ----------------
__global__ void __launch_bounds__(256) k_mean(const float* __restrict__ bb,
                                              float* __restrict__ mean) {
    int tid = blockIdx.x * blockDim.x + threadIdx.x;
    int b = tid >> 5;
    int d = (tid & 31) * 4;
    const float4* p = (const float4*)(bb + (size_t)b * (NG * BDIM) + d);
    float4 s = {0.f, 0.f, 0.f, 0.f};
    #pragma unroll
    for (int g = 0; g < NG; ++g) {
        float4 v = p[g * (BDIM / 4)];
        s.x += v.x; s.y += v.y; s.z += v.z; s.w += v.w;
    }
    s.x *= 0.0625f; s.y *= 0.0625f; s.z *= 0.0625f; s.w *= 0.0625f;
    *(float4*)(mean + (size_t)b * BDIM + d) = s;
}

// ---- new_RF = mish(RF@Wrfrf^T+b1) + mish(mean@Wbbrf^T+b2); also rf2bb slices ----
// 512 blocks x 256 thr; block tile 128(M)x64(N); wave tile 64x32; dbuf LDS, 1 barrier/iter.
__global__ void __launch_bounds__(256) k_newrf(
    const float* __restrict__ rf,     // [4096,1024]
    const float* __restrict__ meanp,  // [4096,128]
    const float* __restrict__ Wrfrf,  // [1024,1024]
    const float* __restrict__ brfrf,  // [1024]
    const float* __restrict__ Wbbrf,  // [1024,128]
    const float* __restrict__ bbbrf,  // [1024]
    const float* __restrict__ Wrfbb,  // [128,1024]
    const float* __restrict__ brfbb,  // [128]
    float* __restrict__ out,          // [4096,1024]
    float* __restrict__ rf2bb)        // [4096,128] ws fp32
{
    __shared__ short As[2][128 * LDP];
    __shared__ short Bs[2][64 * LDP];
    __shared__ short Ws2[2][16 * LDP];
    int tid = threadIdx.x;
    int wave = tid >> 6, lane = tid & 63;
    int r = lane & 15, quad = lane >> 4;
    int wm = (wave & 1) * 64, wn = (wave >> 1) * 32;
    int mt = blockIdx.x >> 4, nt = blockIdx.x & 15;
    int m0 = mt * 128, n0 = nt * 64;
    bool doP = (nt < 8);

    int arow = tid >> 1, akh = (tid & 1) * 16;
    int brow = tid >> 2, bkq = (tid & 3) * 8;
    int aidx = arow * LDP + akh;
    int bidx = brow * LDP + bkq;
    int widx = (tid >> 2) * LDP + bkq;           // tid<64 only

    const float* aG = rf    + (size_t)(m0 + arow) * RDIM + akh;
    const float* bG = Wrfrf + (size_t)(n0 + brow) * RDIM + bkq;
    const float* wG = Wrfbb + (size_t)(nt * 16 + (tid >> 2)) * RDIM + bkq; // tid<64

    floatx4 acc1[4][2], acc2[4][2], acc3[4];
    #pragma unroll
    for (int mi = 0; mi < 4; ++mi) {
        acc1[mi][0] = floatx4{0.f,0.f,0.f,0.f}; acc1[mi][1] = acc1[mi][0];
        acc2[mi][0] = acc1[mi][0]; acc2[mi][1] = acc1[mi][0];
        acc3[mi] = acc1[mi][0];
    }
    float4 ra0, ra1, ra2, ra3, rb0, rb1, rw0, rw1;
    bool wload = doP && (tid < 64);

    // preload tile0 -> regs -> buf0, then load tile1
    ra0 = ((const float4*)aG)[0]; ra1 = ((const float4*)aG)[1];
    ra2 = ((const float4*)aG)[2]; ra3 = ((const float4*)aG)[3];
    rb0 = ((const float4*)bG)[0]; rb1 = ((const float4*)bG)[1];
    if (wload) { rw0 = ((const float4*)wG)[0]; rw1 = ((const float4*)wG)[1]; }
    *(short8*)&As[0][aidx]     = cvt8v(ra0, ra1);
    *(short8*)&As[0][aidx + 8] = cvt8v(ra2, ra3);
    *(short8*)&Bs[0][bidx]     = cvt8v(rb0, rb1);
    if (wload) *(short8*)&Ws2[0][widx] = cvt8v(rw0, rw1);
    ra0 = ((const float4*)(aG + 32))[0]; ra1 = ((const float4*)(aG + 32))[1];
    ra2 = ((const float4*)(aG + 32))[2]; ra3 = ((const float4*)(aG + 32))[3];
    rb0 = ((const float4*)(bG + 32))[0]; rb1 = ((const float4*)(bG + 32))[1];
    if (wload) { rw0 = ((const float4*)(wG + 32))[0]; rw1 = ((const float4*)(wG + 32))[1]; }
    __syncthreads();

    for (int it = 0; it < 32; ++it) {
        const short* Ac = As[it & 1];
        const short* Bc = Bs[it & 1];
        const short* Wc = Ws2[it & 1];
        short8 af[4];
        #pragma unroll
        for (int mi = 0; mi < 4; ++mi)
            af[mi] = *(const short8*)&Ac[(wm + mi * 16 + r) * LDP + quad * 8];
        short8 bf[2];
        bf[0] = *(const short8*)&Bc[(wn + r) * LDP + quad * 8];
        bf[1] = *(const short8*)&Bc[(wn + 16 + r) * LDP + quad * 8];
        #pragma unroll
        for (int mi = 0; mi < 4; ++mi) {
            acc1[mi][0] = MFMA(af[mi], bf[0], acc1[mi][0]);
            acc1[mi][1] = MFMA(af[mi], bf[1], acc1[mi][1]);
        }
        if (doP && (wave & 2) == 0) {
            short8 b2 = *(const short8*)&Wc[r * LDP + quad * 8];
            #pragma unroll
            for (int mi = 0; mi < 4; ++mi) acc3[mi] = MFMA(af[mi], b2, acc3[mi]);
        }
        if (it < 31) {
            int nb = (it + 1) & 1;
            *(short8*)&As[nb][aidx]     = cvt8v(ra0, ra1);
            *(short8*)&As[nb][aidx + 8] = cvt8v(ra2, ra3);
            *(short8*)&Bs[nb][bidx]     = cvt8v(rb0, rb1);
            if (wload) *(short8*)&Ws2[nb][widx] = cvt8v(rw0, rw1);
        }
        if (it < 30) {
            int k = (it + 2) * 32;
            ra0 = ((const float4*)(aG + k))[0]; ra1 = ((const float4*)(aG + k))[1];
            ra2 = ((const float4*)(aG + k))[2]; ra3 = ((const float4*)(aG + k))[3];
            rb0 = ((const float4*)(bG + k))[0]; rb1 = ((const float4*)(bG + k))[1];
            if (wload) { rw0 = ((const float4*)(wG + k))[0]; rw1 = ((const float4*)(wG + k))[1]; }
        }
        __syncthreads();
    }

    // ---- GEMM2: mean @ Wbbrf^T, K=128 (4 dbuf iters) ----
    const float* a2G = meanp + (size_t)(m0 + arow) * BDIM + akh;
    const float* b2G = Wbbrf + (size_t)(n0 + brow) * BDIM + bkq;
    ra0 = ((const float4*)a2G)[0]; ra1 = ((const float4*)a2G)[1];
    ra2 = ((const float4*)a2G)[2]; ra3 = ((const float4*)a2G)[3];
    rb0 = ((const float4*)b2G)[0]; rb1 = ((const float4*)b2G)[1];
    *(short8*)&As[0][aidx]     = cvt8v(ra0, ra1);
    *(short8*)&As[0][aidx + 8] = cvt8v(ra2, ra3);
    *(short8*)&Bs[0][bidx]     = cvt8v(rb0, rb1);
    ra0 = ((const float4*)(a2G + 32))[0]; ra1 = ((const float4*)(a2G + 32))[1];
    ra2 = ((const float4*)(a2G + 32))[2]; ra3 = ((const float4*)(a2G + 32))[3];
    rb0 = ((const float4*)(b2G + 32))[0]; rb1 = ((const float4*)(b2G + 32))[1];
    __syncthreads();
    for (int it = 0; it < 4; ++it) {
        const short* Ac = As[it & 1];
        const short* Bc = Bs[it & 1];
        short8 af[4];
        #pragma unroll
        for (int mi = 0; mi < 4; ++mi)
            af[mi] = *(const short8*)&Ac[(wm + mi * 16 + r) * LDP + quad * 8];
        short8 bf[2];
        bf[0] = *(const short8*)&Bc[(wn + r) * LDP + quad * 8];
        bf[1] = *(const short8*)&Bc[(wn + 16 + r) * LDP + quad * 8];
        #pragma unroll
        for (int mi = 0; mi < 4; ++mi) {
            acc2[mi][0] = MFMA(af[mi], bf[0], acc2[mi][0]);
            acc2[mi][1] = MFMA(af[mi], bf[1], acc2[mi][1]);
        }
        if (it < 3) {
            int nb = (it + 1) & 1;
            *(short8*)&As[nb][aidx]     = cvt8v(ra0, ra1);
            *(short8*)&As[nb][aidx + 8] = cvt8v(ra2, ra3);
            *(short8*)&Bs[nb][bidx]     = cvt8v(rb0, rb1);
        }
        if (it < 2) {
            int k = (it + 2) * 32;
            ra0 = ((const float4*)(a2G + k))[0]; ra1 = ((const float4*)(a2G + k))[1];
            ra2 = ((const float4*)(a2G + k))[2]; ra3 = ((const float4*)(a2G + k))[3];
            rb0 = ((const float4*)(b2G + k))[0]; rb1 = ((const float4*)(b2G + k))[1];
        }
        __syncthreads();
    }

    // ---- epilogue ----
    #pragma unroll
    for (int nj = 0; nj < 2; ++nj) {
        int col = n0 + wn + nj * 16 + r;
        float b1 = brfrf[col];
        float b2 = bbbrf[col];
        #pragma unroll
        for (int mi = 0; mi < 4; ++mi) {
            #pragma unroll
            for (int g = 0; g < 4; ++g) {
                int row = m0 + wm + mi * 16 + quad * 4 + g;
                out[(size_t)row * RDIM + col] =
                    mishf(acc1[mi][nj][g] + b1) + mishf(acc2[mi][nj][g] + b2);
            }
        }
    }
    if (doP && (wave & 2) == 0) {
        int col = nt * 16 + r;
        float bs = brfbb[col];
        #pragma unroll
        for (int mi = 0; mi < 4; ++mi) {
            #pragma unroll
            for (int g = 0; g < 4; ++g) {
                int row = m0 + wm + mi * 16 + quad * 4 + g;
                rf2bb[(size_t)row * BDIM + col] = mishf(acc3[mi][g] + bs);
            }
        }
    }
}

// ---------------- new_BB = mish(BB @ W_bbbb^T + b) + RF_to_BB[b] ----------------
// 512 blocks x 256 thr; W staged once; A dbuf'd, 1 barrier/iter.
__global__ void __launch_bounds__(256) k_newbb(
    const float* __restrict__ bb,    // [65536,128]
    const float* __restrict__ W,     // [128,128]
    const float* __restrict__ bias,  // [128]
    const float* __restrict__ rf2bb, // [4096,128]
    float* __restrict__ out)         // [65536,128]
{
    __shared__ short Wt[128 * WSTR];
    __shared__ short As[2][128 * LDP];
    int tid = threadIdx.x;
    int wave = tid >> 6, lane = tid & 63;
    int r = lane & 15, quad = lane >> 4;
    size_t m0 = (size_t)blockIdx.x * 128;

    // stage full W (128x128) once: thread -> row=tid>>1, half=(tid&1)*64
    {
        int row = tid >> 1, half = (tid & 1) * 64;
        const float* wp = W + (size_t)row * BDIM + half;
        #pragma unroll
        for (int j = 0; j < 8; ++j) {
            float4 f0 = ((const float4*)(wp + j * 8))[0];
            float4 f1 = ((const float4*)(wp + j * 8))[1];
            *(short8*)&Wt[row * WSTR + half + j * 8] = cvt8v(f0, f1);
        }
    }

    int arow = tid >> 1, akh = (tid & 1) * 16;
    int aidx = arow * LDP + akh;
    const float* aG = bb + (m0 + arow) * BDIM + akh;

    floatx4 acc[2][8];
    #pragma unroll
    for (int i = 0; i < 2; ++i)
        #pragma unroll
        for (int j = 0; j < 8; ++j) acc[i][j] = floatx4{0.f,0.f,0.f,0.f};

    float4 ra0, ra1, ra2, ra3;
    ra0 = ((const float4*)aG)[0]; ra1 = ((const float4*)aG)[1];
    ra2 = ((const float4*)aG)[2]; ra3 = ((const float4*)aG)[3];
    *(short8*)&As[0][aidx]     = cvt8v(ra0, ra1);
    *(short8*)&As[0][aidx + 8] = cvt8v(ra2, ra3);
    ra0 = ((const float4*)(aG + 32))[0]; ra1 = ((const float4*)(aG + 32))[1];
    ra2 = ((const float4*)(aG + 32))[2]; ra3 = ((const float4*)(aG + 32))[3];
    __syncthreads();

    for (int kc = 0; kc < 4; ++kc) {
        const short* Ac = As[kc & 1];
        short8 a0 = *(const short8*)&Ac[(wave * 32 + r) * LDP + quad * 8];
        short8 a1 = *(const short8*)&Ac[(wave * 32 + 16 + r) * LDP + quad * 8];
        #pragma unroll
        for (int nj = 0; nj < 8; ++nj) {
            short8 b = *(const short8*)&Wt[(nj * 16 + r) * WSTR + kc * 32 + quad * 8];
            acc[0][nj] = MFMA(a0, b, acc[0][nj]);
            acc[1][nj] = MFMA(a1, b, acc[1][nj]);
        }
        if (kc < 3) {
            int nb = (kc + 1) & 1;
            *(short8*)&As[nb][aidx]     = cvt8v(ra0, ra1);
            *(short8*)&As[nb][aidx + 8] = cvt8v(ra2, ra3);
        }
        if (kc < 2) {
            int k = (kc + 2) * 32;
            ra0 = ((const float4*)(aG + k))[0]; ra1 = ((const float4*)(aG + k))[1];
            ra2 = ((const float4*)(aG + k))[2]; ra3 = ((const float4*)(aG + k))[3];
        }
        __syncthreads();
    }

    #pragma unroll
    for (int mi = 0; mi < 2; ++mi) {
        #pragma unroll
        for (int nj = 0; nj < 8; ++nj) {
            int col = nj * 16 + r;
            float bs = bias[col];
            #pragma unroll
            for (int g = 0; g < 4; ++g) {
                size_t row = m0 + wave * 32 + mi * 16 + quad * 4 + g;
                out[row * BDIM + col] = mishf(acc[mi][nj][g] + bs) + rf2bb[(row >> 4) * BDIM + col];
            }
        }
    }
}

extern "C" void kernel_launch(void* const* d_in, const int* in_sizes, int n_in,
                              void* d_out, int out_size, void* d_ws, size_t ws_size,
                              hipStream_t stream) {
    const float* BB    = (const float*)d_in[0];
    const float* RF    = (const float*)d_in[1];
    const float* Wrfbb = (const float*)d_in[2];
    const float* brfbb = (const float*)d_in[3];
    const float* Wrfrf = (const float*)d_in[4];
    const float* brfrf = (const float*)d_in[5];
    const float* Wbbrf = (const float*)d_in[6];
    const float* bbbrf = (const float*)d_in[7];
    const float* Wbbbb = (const float*)d_in[8];
    const float* bbbbb = (const float*)d_in[9];

    float* outBB = (float*)d_out;
    float* outRF = outBB + (size_t)NB * NG * BDIM;

    float* mean  = (float*)d_ws;
    float* rf2bb = (float*)((char*)d_ws + (size_t)NB * BDIM * 4);

    k_mean <<<512, 256, 0, stream>>>(BB, mean);
    k_newrf<<<512, 256, 0, stream>>>(RF, mean, Wrfrf, brfrf, Wbbrf, bbbrf,
                                     Wrfbb, brfbb, outRF, rf2bb);
    k_newbb<<<512, 256, 0, stream>>>(BB, Wbbbb, bbbbb, rf2bb, outBB);
}